// Round 6
// baseline (394.252 us; speedup 1.0000x reference)
//
#include <hip/hip_runtime.h>
#include <cstddef>

// PseudoSpectra2d: out = B1 @ (LocalConv3x3_posdep( pad(A1[:64]@u@A2[:64]^T) , W)) @ B2^T
// B=16, CIN=COUT=32, H=W=128, M1=M2=64, KH=KW=3, pad=1
// ws layout: bpi [16][32][64][64] f32 (8 MB)
//            out2p [NCH][16][32][64][64] f32 (8 MB per chunk) at offset 8 MB

#define NB 16
#define NCIN 32
#define NCOUT 32

typedef float f32x4 __attribute__((ext_vector_type(4)));

__device__ __forceinline__ float dpp_shr1(float x) {  // lane i <- lane i-1 (16-lane rows), edge -> 0
  int r = __builtin_amdgcn_update_dpp(0, __float_as_int(x), 0x111, 0xF, 0xF, true);
  return __int_as_float(r);
}
__device__ __forceinline__ float dpp_shl1(float x) {  // lane i <- lane i+1 (16-lane rows), edge -> 0
  int r = __builtin_amdgcn_update_dpp(0, __float_as_int(x), 0x101, 0xF, 0xF, true);
  return __int_as_float(r);
}
__device__ __forceinline__ float4 f4add(float4 a, float4 b) {
  return make_float4(a.x + b.x, a.y + b.y, a.z + b.z, a.w + b.w);
}
__device__ __forceinline__ void nt_store4(float* p, float a, float b, float c, float d) {
  f32x4 v; v.x = a; v.y = b; v.z = c; v.w = d;
  __builtin_nontemporal_store(v, (f32x4*)p);
}

// ---------------------------------------------------------------------------
// K1: per (b,c): T[h][k] = sum_w u[h][w]*A2[k][w]; bp[m][k] = sum_h A1[m][h]*T[h][k]
// u/A1 operands via VMEM broadcast (4 addrs/wave, L1/L2-hot); A2^T and T via ds_read_b128.
// LDS 69.6 KB -> 2 blocks/CU (16 waves/CU).
// ---------------------------------------------------------------------------
__global__ __launch_bounds__(256) void k1_spectral(const float* __restrict__ u,
                                                   const float* __restrict__ A1,
                                                   const float* __restrict__ A2,
                                                   float* __restrict__ bpi) {
  __shared__ float a2t[128 * 68];   // [w][k] transposed, stride 68
  __shared__ float t_s[128 * 68];   // [h][k], stride 68
  const int tid = threadIdx.x;
  const int bc = blockIdx.x;        // b*32 + c
  const float* up = u + (size_t)bc * 16384;

  // stage A2^T: a2t[w][k] = A2[k][w]  (k < 64)
#pragma unroll
  for (int it = 0; it < 8; ++it) {
    int f = it * 256 + tid;          // 2048 float4 over 64x128
    int k = f >> 5;
    int w4 = (f & 31) * 4;
    float4 v = *(const float4*)(A2 + k * 128 + w4);
    a2t[(w4 + 0) * 68 + k] = v.x;
    a2t[(w4 + 1) * 68 + k] = v.y;
    a2t[(w4 + 2) * 68 + k] = v.z;
    a2t[(w4 + 3) * 68 + k] = v.w;
  }
  __syncthreads();

  // Phase B: T[h][k], tile 8h x 4k per thread (threads (16,16))
  {
    const int h0 = (tid >> 4) * 8;
    const int k0 = (tid & 15) * 4;
    float acc[8][4] = {};
#pragma unroll 2
    for (int w4 = 0; w4 < 128; w4 += 4) {
      float4 uv[8];
#pragma unroll
      for (int i = 0; i < 8; ++i)
        uv[i] = *(const float4*)(up + (h0 + i) * 128 + w4);
      float4 av[4];
#pragma unroll
      for (int dw = 0; dw < 4; ++dw)
        av[dw] = *(const float4*)(a2t + (w4 + dw) * 68 + k0);
#pragma unroll
      for (int i = 0; i < 8; ++i) {
        const float* up_ = (const float*)&uv[i];
#pragma unroll
        for (int dw = 0; dw < 4; ++dw) {
          const float* ap = (const float*)&av[dw];
          float uval = up_[dw];
#pragma unroll
          for (int j = 0; j < 4; ++j) acc[i][j] += uval * ap[j];
        }
      }
    }
#pragma unroll
    for (int i = 0; i < 8; ++i)
      *(float4*)(t_s + (h0 + i) * 68 + k0) =
          make_float4(acc[i][0], acc[i][1], acc[i][2], acc[i][3]);
  }
  __syncthreads();

  // Phase C: bp[m][k], tile 4m x 4k per thread (threads (16,16))
  {
    const int m0 = (tid >> 4) * 4;
    const int k0 = (tid & 15) * 4;
    float acc[4][4] = {};
#pragma unroll 2
    for (int h4 = 0; h4 < 128; h4 += 4) {
      float4 a1v[4];
#pragma unroll
      for (int i = 0; i < 4; ++i)
        a1v[i] = *(const float4*)(A1 + (m0 + i) * 128 + h4);
      float4 tv[4];
#pragma unroll
      for (int dh = 0; dh < 4; ++dh)
        tv[dh] = *(const float4*)(t_s + (h4 + dh) * 68 + k0);
#pragma unroll
      for (int i = 0; i < 4; ++i) {
        const float* ap = (const float*)&a1v[i];
#pragma unroll
        for (int dh = 0; dh < 4; ++dh) {
          const float* tp = (const float*)&tv[dh];
          float aval = ap[dh];
#pragma unroll
          for (int j = 0; j < 4; ++j) acc[i][j] += aval * tp[j];
        }
      }
    }
    float* bp = bpi + (size_t)bc * 4096;
#pragma unroll
    for (int i = 0; i < 4; ++i)
      nt_store4(bp + (m0 + i) * 64 + k0, acc[i][0], acc[i][1], acc[i][2], acc[i][3]);
  }
}

// ---------------------------------------------------------------------------
// K2: out2[b][o][xi][xj] = sum_{c,ki,kj} xpad(b,c,xi-1+ki,xj-1+kj) * W[c*9+ki*3+kj][o][xi*64+xj]
// No LDS/barriers. Lanes: (xjg:16, lbg:4); wave: 8 b x 2 o. Halo via DPP (bound_ctrl=0 = zero pad).
// c-loop split into gridDim.z chunks of CPC -> 2048 blocks (CPC=8) = 32 waves/CU.
// Each chunk writes its own partial out2p[cz]; k3 sums them.
// ---------------------------------------------------------------------------
template <int CPC>
__global__ __launch_bounds__(256) void k2_conv(const float* __restrict__ bpi,
                                               const float* __restrict__ Wt,
                                               float* __restrict__ out2p) {
  const int tid = threadIdx.x;
  const int lane = tid & 63;
  const int wv = tid >> 6;           // 0..3
  const int xjg = lane & 15;         // f4 col group
  const int lbg = lane >> 4;         // 0..3
  const int bid = blockIdx.x;        // 0..63
  const int xi = ((bid & 7) << 3) | (bid >> 3);   // XCD-swizzle: XCD x owns xi in [8x, 8x+8)
  const int og = blockIdx.y;         // 0..7
  const int cz = blockIdx.z;
  const int c0 = cz * CPC;
  const int bg = wv >> 1;
  const int op = wv & 1;
  const int o0 = og * 4 + op * 2;    // wave's o0, o0+1
  const int b0 = bg * 8 + lbg * 2;   // lane's b0, b0+1

  float acc[2][2][4] = {};           // [rb][oo][x]

  for (int cc = 0; cc < CPC; ++cc) {
    const int c = c0 + cc;
    float4 xv[2][3];
#pragma unroll
    for (int ki = 0; ki < 3; ++ki) {
      const int row = xi - 1 + ki;
      const bool valid = (row >= 0) && (row < 64);   // wave-uniform
#pragma unroll
      for (int rb = 0; rb < 2; ++rb) {
        if (valid)
          xv[rb][ki] = *(const float4*)(bpi +
              (((size_t)(b0 + rb) * NCIN + c) * 64 + row) * 64 + xjg * 4);
        else
          xv[rb][ki] = make_float4(0.f, 0.f, 0.f, 0.f);
      }
    }
    float4 wr[9][2];
    const float* wbase = Wt + (((size_t)c * 9) * NCOUT + o0) * 4096 + xi * 64 + xjg * 4;
#pragma unroll
    for (int t = 0; t < 9; ++t) {
#pragma unroll
      for (int oo = 0; oo < 2; ++oo)
        wr[t][oo] = *(const float4*)(wbase + ((size_t)t * NCOUT + oo) * 4096);
    }
#pragma unroll
    for (int ki = 0; ki < 3; ++ki) {
#pragma unroll
      for (int rb = 0; rb < 2; ++rb) {
        float xw[6];
        xw[1] = xv[rb][ki].x; xw[2] = xv[rb][ki].y;
        xw[3] = xv[rb][ki].z; xw[4] = xv[rb][ki].w;
        xw[0] = dpp_shr1(xv[rb][ki].w);   // col xj-1 (0 at left edge = pad)
        xw[5] = dpp_shl1(xv[rb][ki].x);   // col xj+4 (0 at right edge = pad)
#pragma unroll
        for (int kj = 0; kj < 3; ++kj) {
          const int t = ki * 3 + kj;
#pragma unroll
          for (int oo = 0; oo < 2; ++oo) {
            const float* w = (const float*)&wr[t][oo];
#pragma unroll
            for (int x = 0; x < 4; ++x)
              acc[rb][oo][x] += xw[x + kj] * w[x];
          }
        }
      }
    }
  }
  float* dst0 = out2p + (size_t)cz * (NB * NCOUT * 4096);
#pragma unroll
  for (int rb = 0; rb < 2; ++rb)
#pragma unroll
    for (int oo = 0; oo < 2; ++oo)
      nt_store4(dst0 + ((size_t)(b0 + rb) * NCOUT + (o0 + oo)) * 4096 + xi * 64 + xjg * 4,
                acc[rb][oo][0], acc[rb][oo][1], acc[rb][oo][2], acc[rb][oo][3]);
}

// ---------------------------------------------------------------------------
// K3: per (b,o): T2[m][w] = sum_k out2[m][k]*B2[w][k];  R[h][w] = sum_m B1[h][m]*T2[m][w]
// out2 = sum of NCH partials (streamed, L3-hot). LDS 67.6 KB -> 2 blocks/CU.
// ---------------------------------------------------------------------------
template <int NCH>
__global__ __launch_bounds__(256) void k3_recon(const float* __restrict__ out2p,
                                                const float* __restrict__ B1,
                                                const float* __restrict__ B2,
                                                float* __restrict__ outp) {
  __shared__ float b2t[64 * 132];    // [k][w], stride 132
  __shared__ float t2[64 * 132];     // [m][w], stride 132
  const int tid = threadIdx.x;
  const int bc = blockIdx.x;         // b*32 + o
  const size_t PSTR = (size_t)NB * NCOUT * 4096;

  // stage B2^T: b2t[k][w] = B2[w][k]
#pragma unroll
  for (int it = 0; it < 8; ++it) {
    int f = it * 256 + tid;          // 2048 f4 over 128x64
    int w = f >> 4;
    int k4 = (f & 15) * 4;
    float4 v = *(const float4*)(B2 + w * 64 + k4);
    b2t[(k4 + 0) * 132 + w] = v.x;
    b2t[(k4 + 1) * 132 + w] = v.y;
    b2t[(k4 + 2) * 132 + w] = v.z;
    b2t[(k4 + 3) * 132 + w] = v.w;
  }
  __syncthreads();

  // Phase B3: T2[m][w], tile 8m x 4w (threads (8,32))
  {
    const int m0 = (tid >> 5) * 8;
    const int w0 = (tid & 31) * 4;
    float acc[8][4] = {};
    const float* o2 = out2p + (size_t)bc * 4096;
#pragma unroll 2
    for (int k4 = 0; k4 < 64; k4 += 4) {
      float4 a[8];
#pragma unroll
      for (int i = 0; i < 8; ++i) {
        a[i] = *(const float4*)(o2 + (m0 + i) * 64 + k4);
#pragma unroll
        for (int p = 1; p < NCH; ++p)
          a[i] = f4add(a[i], *(const float4*)(o2 + p * PSTR + (m0 + i) * 64 + k4));
      }
      float4 bb[4];
#pragma unroll
      for (int dk = 0; dk < 4; ++dk) bb[dk] = *(const float4*)(b2t + (k4 + dk) * 132 + w0);
#pragma unroll
      for (int i = 0; i < 8; ++i) {
        const float* ap = (const float*)&a[i];
#pragma unroll
        for (int dk = 0; dk < 4; ++dk) {
          const float* bp = (const float*)&bb[dk];
          float aval = ap[dk];
#pragma unroll
          for (int j = 0; j < 4; ++j) acc[i][j] += aval * bp[j];
        }
      }
    }
    __syncthreads();
#pragma unroll
    for (int i = 0; i < 8; ++i)
      *(float4*)(t2 + (m0 + i) * 132 + w0) =
          make_float4(acc[i][0], acc[i][1], acc[i][2], acc[i][3]);
  }
  __syncthreads();

  // Phase C3: R[h][w], tile 8h x 8w (threads (16,16))
  {
    const int h0 = (tid >> 4) * 8;
    const int w0 = (tid & 15) * 8;
    float acc[8][8] = {};
#pragma unroll 2
    for (int m = 0; m < 64; m += 4) {
      float4 a[8];
#pragma unroll
      for (int i = 0; i < 8; ++i) a[i] = *(const float4*)(B1 + (h0 + i) * 64 + m);
      float4 bb[4][2];
#pragma unroll
      for (int dm = 0; dm < 4; ++dm) {
        bb[dm][0] = *(const float4*)(t2 + (m + dm) * 132 + w0);
        bb[dm][1] = *(const float4*)(t2 + (m + dm) * 132 + w0 + 4);
      }
#pragma unroll
      for (int i = 0; i < 8; ++i) {
        const float* ap = (const float*)&a[i];
#pragma unroll
        for (int dm = 0; dm < 4; ++dm) {
          const float* b0p = (const float*)&bb[dm][0];
          const float* b1p = (const float*)&bb[dm][1];
          float aval = ap[dm];
#pragma unroll
          for (int j = 0; j < 4; ++j) {
            acc[i][j]     += aval * b0p[j];
            acc[i][4 + j] += aval * b1p[j];
          }
        }
      }
    }
    float* rp = outp + (size_t)bc * 16384;
#pragma unroll
    for (int i = 0; i < 8; ++i) {
      *(float4*)(rp + (h0 + i) * 128 + w0) =
          make_float4(acc[i][0], acc[i][1], acc[i][2], acc[i][3]);
      *(float4*)(rp + (h0 + i) * 128 + w0 + 4) =
          make_float4(acc[i][4], acc[i][5], acc[i][6], acc[i][7]);
    }
  }
}

extern "C" void kernel_launch(void* const* d_in, const int* in_sizes, int n_in,
                              void* d_out, int out_size, void* d_ws, size_t ws_size,
                              hipStream_t stream) {
  (void)in_sizes; (void)n_in; (void)out_size;
  const float* u  = (const float*)d_in[0];
  const float* A1 = (const float*)d_in[1];
  const float* A2 = (const float*)d_in[2];
  const float* B1 = (const float*)d_in[3];
  const float* B2 = (const float*)d_in[4];
  const float* Wt = (const float*)d_in[5];
  float* out = (float*)d_out;

  const size_t SEG = (size_t)NB * NCIN * 4096 * sizeof(float);   // 8 MB
  float* bpi   = (float*)d_ws;
  float* out2p = (float*)((char*)d_ws + SEG);

  k1_spectral<<<NB * NCIN, 256, 0, stream>>>(u, A1, A2, bpi);

  // c-split factor limited by available workspace (ws_size constant per session,
  // so the chosen variant -- and the work done per call -- never changes).
  if (ws_size >= SEG * 5) {
    k2_conv<8><<<dim3(64, 8, 4), 256, 0, stream>>>(bpi, Wt, out2p);
    k3_recon<4><<<NB * NCOUT, 256, 0, stream>>>(out2p, B1, B2, out);
  } else if (ws_size >= SEG * 3) {
    k2_conv<16><<<dim3(64, 8, 2), 256, 0, stream>>>(bpi, Wt, out2p);
    k3_recon<2><<<NB * NCOUT, 256, 0, stream>>>(out2p, B1, B2, out);
  } else {
    k2_conv<32><<<dim3(64, 8, 1), 256, 0, stream>>>(bpi, Wt, out2p);
    k3_recon<1><<<NB * NCOUT, 256, 0, stream>>>(out2p, B1, B2, out);
  }
}